// Round 16
// baseline (19555.414 us; speedup 1.0000x reference)
//
#include <hip/hip_runtime.h>
#include <cmath>

#define B_ 256
#define T_ 512
#define WASH 64
#define TOUT 448
#define NT 512
#define NBLK 256

/* ---- ws layout (float index) ---- */
#define SRING_OFF 0               /* [4][2][256][256] state ring        */
#define LRING_OFF 524288          /* [4][32 rg8][4 cb][16] logit parts  */
#define SFLAG_OFF 532480          /* [2][64 rg4] stride 32 dwords       */
#define LFLAG_OFF 536576          /* [32 rg8][4 cb] stride 32 dwords    */

__global__ void init_kernel(float* ws) {
    const int i = blockIdx.x * blockDim.x + threadIdx.x;
    if (i < 8192)
        __hip_atomic_store((unsigned*)(ws + SFLAG_OFF) + i, 0u,
                           __ATOMIC_RELAXED, __HIP_MEMORY_SCOPE_AGENT);
}

__global__ void __launch_bounds__(NT, 2)          /* 2 waves/EU -> 256-VGPR cap */
loop_kernel(const int* __restrict__ settings, const float* __restrict__ noiseA,
            const float* __restrict__ noiseB, const float* __restrict__ WinA,
            const float* __restrict__ WrecA, const float* __restrict__ WinB,
            const float* __restrict__ WrecB, const float* __restrict__ Wx,
            const float* __restrict__ bg, const float* __restrict__ Wout,
            const float* __restrict__ bout, float* __restrict__ out, float* ws)
{
    __shared__ float part_raw[16 * 32 * 33];  /* GRU view [16][32][33]; RES view [8][64][17] */
    __shared__ float xbuf[516][8];       /* GRU: x transposed, half-swizzled   */
    __shared__ float sloc[256][4];       /* RES: persistent local state        */
    __shared__ float hz[64][9];          /* GRU: sigmoid(z)                    */
    __shared__ float hn[64][9];          /* GRU: tanh(n)                       */
    __shared__ float bitsf[4];           /* RES */
    __shared__ float dlybuf[4];          /* RES */

    const int tid = threadIdx.x;
    const int bid = blockIdx.x;
    unsigned* sflag = (unsigned*)(ws + SFLAG_OFF);
    unsigned* lflag = (unsigned*)(ws + LFLAG_OFF);
    float* sring = ws + SRING_OFF;
    float* lring = ws + LRING_OFF;
    float* out0 = out;
    float* out1 = out + (size_t)B_ * TOUT;
    float* out2 = out + (size_t)2 * B_ * TOUT;

    if (bid < 128) {
        /* ========== RESERVOIR block: side, 4 rows, FULL side Wrec in regs ==== */
        float (*part)[64][17] = (float (*)[64][17])part_raw;
        const int side = bid & 1, rg4 = bid >> 1;
        const int r0 = rg4 * 4, rg8 = rg4 >> 1, row8b = (rg4 & 1) * 4;
        const int kq = tid >> 6, cg = tid & 63;
        const float* Wr = side ? WrecB : WrecA;
        const float* Wi = side ? WinB : WinA;

        float4 w[32];                                   /* 128 weight VGPRs */
        #pragma unroll
        for (int i = 0; i < 32; ++i)
            w[i] = *(const float4*)(Wr + (size_t)(kq * 32 + i) * 256 + cg * 4);

        const int col = tid >> 1, rp = (tid & 1) * 2;
        const float win0 = Wi[col], win1 = Wi[256 + col];
        const float bo = bout[side];

        for (int i = tid; i < 1024; i += NT) ((float*)sloc)[i] = 0.f;
        __syncthreads();

        unsigned lcache = 0;                 /* monotone flag cache (tid<4) */
        for (int t = 0; t < T_ + 2; ++t) {
            /* ---- poll logit flags >= t-1 (cached, skip when ahead) ---- */
            if (t >= 2 && tid < 4 && lcache < (unsigned)(t - 1)) {
                unsigned* f = lflag + (rg8 * 4 + tid) * 32;
                int g = 0;
                while ((lcache = __hip_atomic_load(f, __ATOMIC_RELAXED,
                                                   __HIP_MEMORY_SCOPE_AGENT))
                       < (unsigned)(t - 1)) {
                    __builtin_amdgcn_s_sleep(1);
                    if (++g > 80000) break;
                }
            }
            __syncthreads();

            /* ---- P1: GEMM -> part ; threads 0..7: bits / delayed+signs ---- */
            if (tid < 4) {
                bitsf[tid] = (t < T_)
                    ? (float)settings[((size_t)(r0 + tid) * T_ + t) * 2 + side] : 0.f;
            } else if (tid < 8) {
                const int rr = tid - 4;
                float s = 0.f;
                if (t >= 2) {
                    const float* lb = lring + ((((size_t)((t - 2) & 3)) * 32 + rg8) * 4) * 16
                                      + (row8b + rr) * 2 + side;
                    #pragma unroll
                    for (int cb = 0; cb < 4; ++cb)
                        s += __hip_atomic_load(lb + cb * 16, __ATOMIC_RELAXED,
                                               __HIP_MEMORY_SCOPE_AGENT);
                    s += bo;
                    if (t - 2 >= WASH) {
                        const float sg = (s > 0.f) ? 1.f : ((s < 0.f) ? -1.f : 0.f);
                        __builtin_nontemporal_store(sg,
                            (side ? out1 : out0) + (size_t)(r0 + rr) * TOUT + (t - 2 - WASH));
                    }
                }
                dlybuf[rr] = s;
            }
            if (t < T_) {
                float a00=0,a01=0,a02=0,a03=0, a10=0,a11=0,a12=0,a13=0;
                float a20=0,a21=0,a22=0,a23=0, a30=0,a31=0,a32=0,a33=0;
                #pragma unroll
                for (int i = 0; i < 32; ++i) {
                    const float4 w4 = w[i];
                    const float4 s4 = *(const float4*)&sloc[kq * 32 + i][0];
                    a00 = fmaf(s4.x, w4.x, a00); a10 = fmaf(s4.y, w4.x, a10);
                    a20 = fmaf(s4.z, w4.x, a20); a30 = fmaf(s4.w, w4.x, a30);
                    a01 = fmaf(s4.x, w4.y, a01); a11 = fmaf(s4.y, w4.y, a11);
                    a21 = fmaf(s4.z, w4.y, a21); a31 = fmaf(s4.w, w4.y, a31);
                    a02 = fmaf(s4.x, w4.z, a02); a12 = fmaf(s4.y, w4.z, a12);
                    a22 = fmaf(s4.z, w4.z, a22); a32 = fmaf(s4.w, w4.z, a32);
                    a03 = fmaf(s4.x, w4.w, a03); a13 = fmaf(s4.y, w4.w, a13);
                    a23 = fmaf(s4.z, w4.w, a23); a33 = fmaf(s4.w, w4.w, a33);
                }
                float* pb = &part[kq][cg][0];
                pb[0]=a00; pb[1]=a10; pb[2]=a20; pb[3]=a30;
                pb[4]=a01; pb[5]=a11; pb[6]=a21; pb[7]=a31;
                pb[8]=a02; pb[9]=a12; pb[10]=a22; pb[11]=a32;
                pb[12]=a03; pb[13]=a13; pb[14]=a23; pb[15]=a33;
            }
            __syncthreads();

            /* ---- P2: reduce + inputs + tanh -> sloc ---- */
            if (t < T_) {
                #pragma unroll
                for (int r = 0; r < 2; ++r) {
                    float e = 0.f;
                    #pragma unroll
                    for (int q = 0; q < 8; ++q)
                        e += part[q][col >> 2][(col & 3) * 4 + rp + r];
                    e += bitsf[rp + r] * win0 + dlybuf[rp + r] * win1;
                    sloc[col][rp + r] = tanhf(e);
                }
            }
            __syncthreads();

            /* ---- P3: contiguous publish + flag ---- */
            if (t < T_) {
                #pragma unroll
                for (int e = 0; e < 2; ++e) {
                    const int idx = tid + e * NT;
                    const int prow = idx >> 8, pcol = idx & 255;
                    __hip_atomic_store(
                        sring + ((size_t)(((t + 1) & 3) * 2 + side) * 256 + r0 + prow) * 256 + pcol,
                        sloc[pcol][prow], __ATOMIC_RELAXED, __HIP_MEMORY_SCOPE_AGENT);
                }
            }
            __syncthreads();
            if (t < T_ && tid == 0) {
                asm volatile("s_waitcnt vmcnt(0)" ::: "memory");
                __hip_atomic_fetch_add(sflag + (side * 64 + rg4) * 32, 1u,
                                       __ATOMIC_RELAXED, __HIP_MEMORY_SCOPE_AGENT);
            }
        }
    } else {
        /* ========== GRU block: 8 rows x 64 h-dims; 4 cols/thread, 2 row-passes */
        float (*partG)[32][33] = (float (*)[32][33])part_raw;
        const int g = bid - 128, rg8 = g >> 2, cb = g & 3, r0 = rg8 * 8;
        const int kq = tid >> 5, cg = tid & 31;         /* 16 k-chunks x 32 cg */
        const int zc0 = cb * 64 + 2 * cg;
        const int nc0_ = 512 + zc0;

        float wz0[34], wz1[34], wn0[34], wn1[34];       /* 136 weight VGPRs */
        #pragma unroll
        for (int i = 0; i < 34; ++i) {
            const int k = kq * 32 + i;
            const bool v = (i < 32) || (kq == 15);      /* pads zeroed */
            wz0[i] = v ? Wx[(size_t)k * 768 + zc0]      : 0.f;
            wz1[i] = v ? Wx[(size_t)k * 768 + zc0 + 1]  : 0.f;
            wn0[i] = v ? Wx[(size_t)k * 768 + nc0_]     : 0.f;
            wn1[i] = v ? Wx[(size_t)k * 768 + nc0_ + 1] : 0.f;
        }
        const int hd = tid >> 3, rs4 = (tid >> 1) & 3, zn = tid & 1;
        const float bgr = zn ? bg[512 + cb * 64 + hd] : bg[cb * 64 + hd];
        const int rcg = hd >> 1;                         /* reduce col-group  */
        const int rci = (zn ? 2 : 0) + (hd & 1);         /* partial col index */
        const int wv = tid >> 6, lane = tid & 63, lj = wv & 1;
        const float wo = Wout[(cb * 64 + lane) * 2 + lj];

        const int xk = tid;
        const int sd = (xk < 256) ? 0 : 1;
        const int nc0 = xk & 255;
        const float* npb = (sd ? noiseB : noiseA) + (size_t)r0 * T_ * 256 + nc0;
        float nz[8];
        #pragma unroll
        for (int r = 0; r < 8; ++r) nz[r] = npb[(size_t)r * T_ * 256];

        unsigned scache = 0;                 /* monotone flag cache (tid<4) */
        for (int u = 0; u < T_; ++u) {
            /* ---- poll state flags >= u (cached, relaxed) ---- */
            if (u > 0 && tid < 4 && scache < (unsigned)u) {
                unsigned* f = sflag + ((tid & 1) * 64 + rg8 * 2 + (tid >> 1)) * 32;
                int gg = 0;
                while ((scache = __hip_atomic_load(f, __ATOMIC_RELAXED,
                                                   __HIP_MEMORY_SCOPE_AGENT))
                       < (unsigned)u) {
                    __builtin_amdgcn_s_sleep(1);
                    if (++gg > 80000) break;
                }
            }
            __syncthreads();

            /* ---- B: x-build (gather state + noise, 8 rows/thread) ---- */
            {
                float sv[8];
                #pragma unroll
                for (int r = 0; r < 8; ++r) sv[r] = 0.f;
                if (u > 0) {
                    const float* sb = sring
                        + ((size_t)((u & 3) * 2 + sd) * 256 + r0) * 256 + nc0;
                    #pragma unroll
                    for (int r = 0; r < 8; ++r)
                        sv[r] = __hip_atomic_load(sb + (size_t)r * 256,
                                                  __ATOMIC_RELAXED, __HIP_MEMORY_SCOPE_AGENT);
                }
                const int b = (xk >> 2) & 1;
                *(float4*)&xbuf[xk][4 * b] =
                    make_float4(sv[0] + nz[0], sv[1] + nz[1], sv[2] + nz[2], sv[3] + nz[3]);
                *(float4*)&xbuf[xk][4 - 4 * b] =
                    make_float4(sv[4] + nz[4], sv[5] + nz[5], sv[6] + nz[6], sv[7] + nz[7]);
            }
            if (tid < 16) {                          /* spins + settings log */
                const int rr = tid >> 1, jj = tid & 1;
                const int bv = settings[((size_t)(r0 + rr) * T_ + u) * 2 + jj];
                xbuf[512 + jj][rr] = 2.f * (float)bv - 1.f;
                if (cb == 0 && u >= WASH)
                    __builtin_nontemporal_store((float)bv,
                        out2 + ((size_t)(r0 + rr) * TOUT + (u - WASH)) * 2 + jj);
            }
            __syncthreads();

            /* ---- C: GEMM -> partG, 4 cols x 8 rows in TWO row-passes ---- */
            {
                const int un = (u + 1 < T_) ? u + 1 : u;
                #pragma unroll
                for (int r = 0; r < 8; ++r)
                    nz[r] = npb[(size_t)r * T_ * 256 + (size_t)un * 256];

                float* pb = &partG[kq][cg][0];
                float a00,a01,a02,a03, a10,a11,a12,a13;
                float a20,a21,a22,a23, a30,a31,a32,a33;

                /* pass 1: rows 0-3 (xa half only) */
                a00=0;a01=0;a02=0;a03=0; a10=0;a11=0;a12=0;a13=0;
                a20=0;a21=0;a22=0;a23=0; a30=0;a31=0;a32=0;a33=0;
                #pragma unroll
                for (int i = 0; i < 34; ++i) {
                    const int k = kq * 32 + i;
                    const float4 xa = *(const float4*)&xbuf[k][4 * ((k >> 2) & 1)];
                    const float w0 = wz0[i], w1 = wz1[i], w2 = wn0[i], w3 = wn1[i];
                    a00 = fmaf(xa.x, w0, a00); a01 = fmaf(xa.y, w0, a01);
                    a02 = fmaf(xa.z, w0, a02); a03 = fmaf(xa.w, w0, a03);
                    a10 = fmaf(xa.x, w1, a10); a11 = fmaf(xa.y, w1, a11);
                    a12 = fmaf(xa.z, w1, a12); a13 = fmaf(xa.w, w1, a13);
                    a20 = fmaf(xa.x, w2, a20); a21 = fmaf(xa.y, w2, a21);
                    a22 = fmaf(xa.z, w2, a22); a23 = fmaf(xa.w, w2, a23);
                    a30 = fmaf(xa.x, w3, a30); a31 = fmaf(xa.y, w3, a31);
                    a32 = fmaf(xa.z, w3, a32); a33 = fmaf(xa.w, w3, a33);
                }
                pb[0]=a00;  pb[1]=a01;  pb[2]=a02;  pb[3]=a03;
                pb[8]=a10;  pb[9]=a11;  pb[10]=a12; pb[11]=a13;
                pb[16]=a20; pb[17]=a21; pb[18]=a22; pb[19]=a23;
                pb[24]=a30; pb[25]=a31; pb[26]=a32; pb[27]=a33;

                /* pass 2: rows 4-7 (xb half), same 16 acc registers */
                a00=0;a01=0;a02=0;a03=0; a10=0;a11=0;a12=0;a13=0;
                a20=0;a21=0;a22=0;a23=0; a30=0;a31=0;a32=0;a33=0;
                #pragma unroll
                for (int i = 0; i < 34; ++i) {
                    const int k = kq * 32 + i;
                    const float4 xb = *(const float4*)&xbuf[k][4 - 4 * ((k >> 2) & 1)];
                    const float w0 = wz0[i], w1 = wz1[i], w2 = wn0[i], w3 = wn1[i];
                    a00 = fmaf(xb.x, w0, a00); a01 = fmaf(xb.y, w0, a01);
                    a02 = fmaf(xb.z, w0, a02); a03 = fmaf(xb.w, w0, a03);
                    a10 = fmaf(xb.x, w1, a10); a11 = fmaf(xb.y, w1, a11);
                    a12 = fmaf(xb.z, w1, a12); a13 = fmaf(xb.w, w1, a13);
                    a20 = fmaf(xb.x, w2, a20); a21 = fmaf(xb.y, w2, a21);
                    a22 = fmaf(xb.z, w2, a22); a23 = fmaf(xb.w, w2, a23);
                    a30 = fmaf(xb.x, w3, a30); a31 = fmaf(xb.y, w3, a31);
                    a32 = fmaf(xb.z, w3, a32); a33 = fmaf(xb.w, w3, a33);
                }
                pb[4]=a00;  pb[5]=a01;  pb[6]=a02;  pb[7]=a03;
                pb[12]=a10; pb[13]=a11; pb[14]=a12; pb[15]=a13;
                pb[20]=a20; pb[21]=a21; pb[22]=a22; pb[23]=a23;
                pb[28]=a30; pb[29]=a31; pb[30]=a32; pb[31]=a33;
            }
            __syncthreads();

            /* ---- D: reduce 16 partials + activations (2 outputs/thread) ---- */
            {
                #pragma unroll
                for (int h = 0; h < 2; ++h) {
                    const int rsub = rs4 + h * 4;
                    float e = bgr;
                    #pragma unroll
                    for (int q = 0; q < 16; ++q)
                        e += partG[q][rcg][rci * 8 + rsub];
                    if (zn == 0) hz[hd][rsub] = 1.f / (1.f + expf(-e));
                    else         hn[hd][rsub] = tanhf(e);
                }
            }
            __syncthreads();

            /* ---- E: logit partials — 8 waves x TWO reductions = 8 rows x 2 ---- */
            {
                #pragma unroll
                for (int h = 0; h < 2; ++h) {
                    const int lrow2 = (wv >> 1) + h * 4;
                    float p = (1.f - hz[lane][lrow2]) * hn[lane][lrow2] * wo;
                    #pragma unroll
                    for (int s = 32; s; s >>= 1) p += __shfl_down(p, s, 64);
                    if (lane == 0)
                        __hip_atomic_store(
                            lring + (((size_t)(u & 3) * 32 + rg8) * 4 + cb) * 16 + lrow2 * 2 + lj,
                            p, __ATOMIC_RELAXED, __HIP_MEMORY_SCOPE_AGENT);
                }
            }
            __syncthreads();
            if (tid == 0) {
                asm volatile("s_waitcnt vmcnt(0)" ::: "memory");
                __hip_atomic_fetch_add(lflag + (rg8 * 4 + cb) * 32, 1u,
                                       __ATOMIC_RELAXED, __HIP_MEMORY_SCOPE_AGENT);
            }
        }
    }
}

extern "C" void kernel_launch(void* const* d_in, const int* in_sizes, int n_in,
                              void* d_out, int out_size, void* d_ws, size_t ws_size,
                              hipStream_t stream) {
    (void)in_sizes; (void)n_in; (void)ws_size; (void)out_size;
    float* ws = (float*)d_ws;
    hipLaunchKernelGGL(init_kernel, dim3(32), dim3(256), 0, stream, ws);

    const int*   settings = (const int*)d_in[0];
    const float* noiseA   = (const float*)d_in[1];
    const float* noiseB   = (const float*)d_in[2];
    const float* WinA     = (const float*)d_in[3];
    const float* WrecA    = (const float*)d_in[4];
    const float* WinB     = (const float*)d_in[5];
    const float* WrecB    = (const float*)d_in[6];
    const float* Wx       = (const float*)d_in[7];   /* d_in[8] = Wh unused (h0 == 0) */
    const float* bg       = (const float*)d_in[9];
    const float* Wout     = (const float*)d_in[10];
    const float* bout     = (const float*)d_in[11];
    float*       outp     = (float*)d_out;

    void* args[] = { &settings, &noiseA, &noiseB, &WinA, &WrecA, &WinB, &WrecB,
                     &Wx, &bg, &Wout, &bout, &outp, &ws };
    hipLaunchCooperativeKernel((void*)loop_kernel, dim3(NBLK), dim3(NT),
                               args, 0, stream);
}

// Round 17
// 19001.396 us; speedup vs baseline: 1.0292x; 1.0292x over previous
//
#include <hip/hip_runtime.h>
#include <cmath>

#define B_ 256
#define T_ 512
#define WASH 64
#define TOUT 448
#define NT 512
#define NBLK 256

/* ---- ws layout (float index) ---- */
#define SRING_OFF 0               /* [4][2][256][256] state ring        */
#define LRING_OFF 524288          /* [4][32 rg8][4 cb][16] logit parts  */
#define SFLAG_OFF 532480          /* [2][64 rg4] stride 32 dwords       */
#define LFLAG_OFF 536576          /* [32 rg8][4 cb] stride 32 dwords    */

__global__ void init_kernel(float* ws) {
    const int i = blockIdx.x * blockDim.x + threadIdx.x;
    if (i < 8192)
        __hip_atomic_store((unsigned*)(ws + SFLAG_OFF) + i, 0u,
                           __ATOMIC_RELAXED, __HIP_MEMORY_SCOPE_AGENT);
}

__global__ void __launch_bounds__(NT, 2)          /* 2 waves/EU -> 256-VGPR cap */
loop_kernel(const int* __restrict__ settings, const float* __restrict__ noiseA,
            const float* __restrict__ noiseB, const float* __restrict__ WinA,
            const float* __restrict__ WrecA, const float* __restrict__ WinB,
            const float* __restrict__ WrecB, const float* __restrict__ Wx,
            const float* __restrict__ bg, const float* __restrict__ Wout,
            const float* __restrict__ bout, float* __restrict__ out, float* ws)
{
    __shared__ float part_raw[16 * 32 * 33];  /* GRU view [16][32][33]; RES view [8][64][17] */
    __shared__ float xbuf[516][8];       /* GRU: x transposed, half-swizzled   */
    __shared__ float sloc[256][4];       /* RES: persistent local state        */
    __shared__ float hz[64][9];          /* GRU: sigmoid(z)                    */
    __shared__ float hn[64][9];          /* GRU: tanh(n)                       */
    __shared__ float bitsf[4];           /* RES */
    __shared__ float dlybuf[4];          /* RES */

    const int tid = threadIdx.x;
    const int bid = blockIdx.x;
    unsigned* sflag = (unsigned*)(ws + SFLAG_OFF);
    unsigned* lflag = (unsigned*)(ws + LFLAG_OFF);
    float* sring = ws + SRING_OFF;
    float* lring = ws + LRING_OFF;
    float* out0 = out;
    float* out1 = out + (size_t)B_ * TOUT;
    float* out2 = out + (size_t)2 * B_ * TOUT;

    if (bid < 128) {
        /* ========== RESERVOIR block: side, 4 rows, FULL side Wrec in regs ==== */
        float (*part)[64][17] = (float (*)[64][17])part_raw;
        const int side = bid & 1, rg4 = bid >> 1;
        const int r0 = rg4 * 4, rg8 = rg4 >> 1, row8b = (rg4 & 1) * 4;
        const int kq = tid >> 6, cg = tid & 63;
        const float* Wr = side ? WrecB : WrecA;
        const float* Wi = side ? WinB : WinA;

        float4 w[32];                                   /* 128 weight VGPRs */
        #pragma unroll
        for (int i = 0; i < 32; ++i)
            w[i] = *(const float4*)(Wr + (size_t)(kq * 32 + i) * 256 + cg * 4);

        const int col = tid >> 1, rp = (tid & 1) * 2;
        const float win0 = Wi[col], win1 = Wi[256 + col];
        const float bo = bout[side];

        for (int i = tid; i < 1024; i += NT) ((float*)sloc)[i] = 0.f;
        __syncthreads();

        unsigned lcache = 0;                 /* monotone flag cache (tid<4) */
        for (int t = 0; t < T_ + 2; ++t) {
            /* ---- poll logit flags >= t-1 (cached, skip when ahead) ---- */
            if (t >= 2 && tid < 4 && lcache < (unsigned)(t - 1)) {
                unsigned* f = lflag + (rg8 * 4 + tid) * 32;
                int g = 0;
                while ((lcache = __hip_atomic_load(f, __ATOMIC_RELAXED,
                                                   __HIP_MEMORY_SCOPE_AGENT))
                       < (unsigned)(t - 1)) {
                    __builtin_amdgcn_s_sleep(1);
                    if (++g > 80000) break;
                }
            }
            __syncthreads();

            /* ---- P1: GEMM -> part ; threads 0..7: bits / delayed+signs ---- */
            if (tid < 4) {
                bitsf[tid] = (t < T_)
                    ? (float)settings[((size_t)(r0 + tid) * T_ + t) * 2 + side] : 0.f;
            } else if (tid < 8) {
                const int rr = tid - 4;
                float s = 0.f;
                if (t >= 2) {
                    const float* lb = lring + ((((size_t)((t - 2) & 3)) * 32 + rg8) * 4) * 16
                                      + (row8b + rr) * 2 + side;
                    #pragma unroll
                    for (int cb = 0; cb < 4; ++cb)
                        s += __hip_atomic_load(lb + cb * 16, __ATOMIC_RELAXED,
                                               __HIP_MEMORY_SCOPE_AGENT);
                    s += bo;
                    if (t - 2 >= WASH) {
                        const float sg = (s > 0.f) ? 1.f : ((s < 0.f) ? -1.f : 0.f);
                        __builtin_nontemporal_store(sg,
                            (side ? out1 : out0) + (size_t)(r0 + rr) * TOUT + (t - 2 - WASH));
                    }
                }
                dlybuf[rr] = s;
            }
            if (t < T_) {
                float a00=0,a01=0,a02=0,a03=0, a10=0,a11=0,a12=0,a13=0;
                float a20=0,a21=0,a22=0,a23=0, a30=0,a31=0,a32=0,a33=0;
                #pragma unroll
                for (int i = 0; i < 32; ++i) {
                    const float4 w4 = w[i];
                    const float4 s4 = *(const float4*)&sloc[kq * 32 + i][0];
                    a00 = fmaf(s4.x, w4.x, a00); a10 = fmaf(s4.y, w4.x, a10);
                    a20 = fmaf(s4.z, w4.x, a20); a30 = fmaf(s4.w, w4.x, a30);
                    a01 = fmaf(s4.x, w4.y, a01); a11 = fmaf(s4.y, w4.y, a11);
                    a21 = fmaf(s4.z, w4.y, a21); a31 = fmaf(s4.w, w4.y, a31);
                    a02 = fmaf(s4.x, w4.z, a02); a12 = fmaf(s4.y, w4.z, a12);
                    a22 = fmaf(s4.z, w4.z, a22); a32 = fmaf(s4.w, w4.z, a32);
                    a03 = fmaf(s4.x, w4.w, a03); a13 = fmaf(s4.y, w4.w, a13);
                    a23 = fmaf(s4.z, w4.w, a23); a33 = fmaf(s4.w, w4.w, a33);
                }
                float* pb = &part[kq][cg][0];
                pb[0]=a00; pb[1]=a10; pb[2]=a20; pb[3]=a30;
                pb[4]=a01; pb[5]=a11; pb[6]=a21; pb[7]=a31;
                pb[8]=a02; pb[9]=a12; pb[10]=a22; pb[11]=a32;
                pb[12]=a03; pb[13]=a13; pb[14]=a23; pb[15]=a33;
            }
            __syncthreads();

            /* ---- P2: reduce + inputs + tanh -> sloc ---- */
            if (t < T_) {
                #pragma unroll
                for (int r = 0; r < 2; ++r) {
                    float e = 0.f;
                    #pragma unroll
                    for (int q = 0; q < 8; ++q)
                        e += part[q][col >> 2][(col & 3) * 4 + rp + r];
                    e += bitsf[rp + r] * win0 + dlybuf[rp + r] * win1;
                    sloc[col][rp + r] = tanhf(e);
                }
            }
            __syncthreads();

            /* ---- P3: contiguous publish + flag ---- */
            if (t < T_) {
                #pragma unroll
                for (int e = 0; e < 2; ++e) {
                    const int idx = tid + e * NT;
                    const int prow = idx >> 8, pcol = idx & 255;
                    __hip_atomic_store(
                        sring + ((size_t)(((t + 1) & 3) * 2 + side) * 256 + r0 + prow) * 256 + pcol,
                        sloc[pcol][prow], __ATOMIC_RELAXED, __HIP_MEMORY_SCOPE_AGENT);
                }
            }
            __syncthreads();
            if (t < T_ && tid == 0) {
                asm volatile("s_waitcnt vmcnt(0)" ::: "memory");
                __hip_atomic_fetch_add(sflag + (side * 64 + rg4) * 32, 1u,
                                       __ATOMIC_RELAXED, __HIP_MEMORY_SCOPE_AGENT);
            }
        }
    } else {
        /* ========== GRU block: 8 rows x 64 h-dims; 4 cols/thread as ONE
           float4 weight array (reservoir-proven container), 2 row-passes ==== */
        float (*partG)[32][33] = (float (*)[32][33])part_raw;
        const int g = bid - 128, rg8 = g >> 2, cb = g & 3, r0 = rg8 * 8;
        const int kq = tid >> 5, cg = tid & 31;         /* 16 k-chunks x 32 cg */
        const int zc0 = cb * 64 + 2 * cg;
        const int nc0_ = 512 + zc0;

        float4 wq[34];                                   /* 136 weight VGPRs, one quad array */
        #pragma unroll
        for (int i = 0; i < 34; ++i) {
            const int k = kq * 32 + i;
            if ((i < 32) || (kq == 15)) {
                const float2 z2 = *(const float2*)(Wx + (size_t)k * 768 + zc0);
                const float2 n2 = *(const float2*)(Wx + (size_t)k * 768 + nc0_);
                wq[i] = make_float4(z2.x, z2.y, n2.x, n2.y);
            } else {
                wq[i] = make_float4(0.f, 0.f, 0.f, 0.f);
            }
        }
        const int hd = tid >> 3, rs4 = (tid >> 1) & 3, zn = tid & 1;
        const float bgr = zn ? bg[512 + cb * 64 + hd] : bg[cb * 64 + hd];
        const int rcg = hd >> 1;                         /* reduce col-group  */
        const int rci = (zn ? 2 : 0) + (hd & 1);         /* partial col index */
        const int wv = tid >> 6, lane = tid & 63, lj = wv & 1;
        const float wo = Wout[(cb * 64 + lane) * 2 + lj];

        const int xk = tid;
        const int sd = (xk < 256) ? 0 : 1;
        const int nc0 = xk & 255;
        const float* npb = (sd ? noiseB : noiseA) + (size_t)r0 * T_ * 256 + nc0;
        float nz[8];
        #pragma unroll
        for (int r = 0; r < 8; ++r) nz[r] = npb[(size_t)r * T_ * 256];

        unsigned scache = 0;                 /* monotone flag cache (tid<4) */
        for (int u = 0; u < T_; ++u) {
            /* ---- poll state flags >= u (cached, relaxed) ---- */
            if (u > 0 && tid < 4 && scache < (unsigned)u) {
                unsigned* f = sflag + ((tid & 1) * 64 + rg8 * 2 + (tid >> 1)) * 32;
                int gg = 0;
                while ((scache = __hip_atomic_load(f, __ATOMIC_RELAXED,
                                                   __HIP_MEMORY_SCOPE_AGENT))
                       < (unsigned)u) {
                    __builtin_amdgcn_s_sleep(1);
                    if (++gg > 80000) break;
                }
            }
            __syncthreads();

            /* ---- B: x-build (gather state + noise, 8 rows/thread) ---- */
            {
                float sv[8];
                #pragma unroll
                for (int r = 0; r < 8; ++r) sv[r] = 0.f;
                if (u > 0) {
                    const float* sb = sring
                        + ((size_t)((u & 3) * 2 + sd) * 256 + r0) * 256 + nc0;
                    #pragma unroll
                    for (int r = 0; r < 8; ++r)
                        sv[r] = __hip_atomic_load(sb + (size_t)r * 256,
                                                  __ATOMIC_RELAXED, __HIP_MEMORY_SCOPE_AGENT);
                }
                const int b = (xk >> 2) & 1;
                *(float4*)&xbuf[xk][4 * b] =
                    make_float4(sv[0] + nz[0], sv[1] + nz[1], sv[2] + nz[2], sv[3] + nz[3]);
                *(float4*)&xbuf[xk][4 - 4 * b] =
                    make_float4(sv[4] + nz[4], sv[5] + nz[5], sv[6] + nz[6], sv[7] + nz[7]);
            }
            if (tid < 16) {                          /* spins + settings log */
                const int rr = tid >> 1, jj = tid & 1;
                const int bv = settings[((size_t)(r0 + rr) * T_ + u) * 2 + jj];
                xbuf[512 + jj][rr] = 2.f * (float)bv - 1.f;
                if (cb == 0 && u >= WASH)
                    __builtin_nontemporal_store((float)bv,
                        out2 + ((size_t)(r0 + rr) * TOUT + (u - WASH)) * 2 + jj);
            }
            __syncthreads();

            /* ---- C: GEMM -> partG, 4 cols x 8 rows in TWO row-passes ---- */
            {
                const int un = (u + 1 < T_) ? u + 1 : u;
                #pragma unroll
                for (int r = 0; r < 8; ++r)
                    nz[r] = npb[(size_t)r * T_ * 256 + (size_t)un * 256];

                float* pb = &partG[kq][cg][0];
                float a00,a01,a02,a03, a10,a11,a12,a13;
                float a20,a21,a22,a23, a30,a31,a32,a33;

                /* pass 1: rows 0-3 (xa half only) */
                a00=0;a01=0;a02=0;a03=0; a10=0;a11=0;a12=0;a13=0;
                a20=0;a21=0;a22=0;a23=0; a30=0;a31=0;a32=0;a33=0;
                #pragma unroll
                for (int i = 0; i < 34; ++i) {
                    const int k = kq * 32 + i;
                    const float4 xa = *(const float4*)&xbuf[k][4 * ((k >> 2) & 1)];
                    const float4 w4 = wq[i];
                    a00 = fmaf(xa.x, w4.x, a00); a01 = fmaf(xa.y, w4.x, a01);
                    a02 = fmaf(xa.z, w4.x, a02); a03 = fmaf(xa.w, w4.x, a03);
                    a10 = fmaf(xa.x, w4.y, a10); a11 = fmaf(xa.y, w4.y, a11);
                    a12 = fmaf(xa.z, w4.y, a12); a13 = fmaf(xa.w, w4.y, a13);
                    a20 = fmaf(xa.x, w4.z, a20); a21 = fmaf(xa.y, w4.z, a21);
                    a22 = fmaf(xa.z, w4.z, a22); a23 = fmaf(xa.w, w4.z, a23);
                    a30 = fmaf(xa.x, w4.w, a30); a31 = fmaf(xa.y, w4.w, a31);
                    a32 = fmaf(xa.z, w4.w, a32); a33 = fmaf(xa.w, w4.w, a33);
                }
                pb[0]=a00;  pb[1]=a01;  pb[2]=a02;  pb[3]=a03;
                pb[8]=a10;  pb[9]=a11;  pb[10]=a12; pb[11]=a13;
                pb[16]=a20; pb[17]=a21; pb[18]=a22; pb[19]=a23;
                pb[24]=a30; pb[25]=a31; pb[26]=a32; pb[27]=a33;

                /* pass 2: rows 4-7 (xb half), same 16 acc registers */
                a00=0;a01=0;a02=0;a03=0; a10=0;a11=0;a12=0;a13=0;
                a20=0;a21=0;a22=0;a23=0; a30=0;a31=0;a32=0;a33=0;
                #pragma unroll
                for (int i = 0; i < 34; ++i) {
                    const int k = kq * 32 + i;
                    const float4 xb = *(const float4*)&xbuf[k][4 - 4 * ((k >> 2) & 1)];
                    const float4 w4 = wq[i];
                    a00 = fmaf(xb.x, w4.x, a00); a01 = fmaf(xb.y, w4.x, a01);
                    a02 = fmaf(xb.z, w4.x, a02); a03 = fmaf(xb.w, w4.x, a03);
                    a10 = fmaf(xb.x, w4.y, a10); a11 = fmaf(xb.y, w4.y, a11);
                    a12 = fmaf(xb.z, w4.y, a12); a13 = fmaf(xb.w, w4.y, a13);
                    a20 = fmaf(xb.x, w4.z, a20); a21 = fmaf(xb.y, w4.z, a21);
                    a22 = fmaf(xb.z, w4.z, a22); a23 = fmaf(xb.w, w4.z, a23);
                    a30 = fmaf(xb.x, w4.w, a30); a31 = fmaf(xb.y, w4.w, a31);
                    a32 = fmaf(xb.z, w4.w, a32); a33 = fmaf(xb.w, w4.w, a33);
                }
                pb[4]=a00;  pb[5]=a01;  pb[6]=a02;  pb[7]=a03;
                pb[12]=a10; pb[13]=a11; pb[14]=a12; pb[15]=a13;
                pb[20]=a20; pb[21]=a21; pb[22]=a22; pb[23]=a23;
                pb[28]=a30; pb[29]=a31; pb[30]=a32; pb[31]=a33;
            }
            __syncthreads();

            /* ---- D: reduce 16 partials + activations (2 outputs/thread) ---- */
            {
                #pragma unroll
                for (int h = 0; h < 2; ++h) {
                    const int rsub = rs4 + h * 4;
                    float e = bgr;
                    #pragma unroll
                    for (int q = 0; q < 16; ++q)
                        e += partG[q][rcg][rci * 8 + rsub];
                    if (zn == 0) hz[hd][rsub] = 1.f / (1.f + expf(-e));
                    else         hn[hd][rsub] = tanhf(e);
                }
            }
            __syncthreads();

            /* ---- E: logit partials — 8 waves x TWO reductions = 8 rows x 2 ---- */
            {
                #pragma unroll
                for (int h = 0; h < 2; ++h) {
                    const int lrow2 = (wv >> 1) + h * 4;
                    float p = (1.f - hz[lane][lrow2]) * hn[lane][lrow2] * wo;
                    #pragma unroll
                    for (int s = 32; s; s >>= 1) p += __shfl_down(p, s, 64);
                    if (lane == 0)
                        __hip_atomic_store(
                            lring + (((size_t)(u & 3) * 32 + rg8) * 4 + cb) * 16 + lrow2 * 2 + lj,
                            p, __ATOMIC_RELAXED, __HIP_MEMORY_SCOPE_AGENT);
                }
            }
            __syncthreads();
            if (tid == 0) {
                asm volatile("s_waitcnt vmcnt(0)" ::: "memory");
                __hip_atomic_fetch_add(lflag + (rg8 * 4 + cb) * 32, 1u,
                                       __ATOMIC_RELAXED, __HIP_MEMORY_SCOPE_AGENT);
            }
        }
    }
}

extern "C" void kernel_launch(void* const* d_in, const int* in_sizes, int n_in,
                              void* d_out, int out_size, void* d_ws, size_t ws_size,
                              hipStream_t stream) {
    (void)in_sizes; (void)n_in; (void)ws_size; (void)out_size;
    float* ws = (float*)d_ws;
    hipLaunchKernelGGL(init_kernel, dim3(32), dim3(256), 0, stream, ws);

    const int*   settings = (const int*)d_in[0];
    const float* noiseA   = (const float*)d_in[1];
    const float* noiseB   = (const float*)d_in[2];
    const float* WinA     = (const float*)d_in[3];
    const float* WrecA    = (const float*)d_in[4];
    const float* WinB     = (const float*)d_in[5];
    const float* WrecB    = (const float*)d_in[6];
    const float* Wx       = (const float*)d_in[7];   /* d_in[8] = Wh unused (h0 == 0) */
    const float* bg       = (const float*)d_in[9];
    const float* Wout     = (const float*)d_in[10];
    const float* bout     = (const float*)d_in[11];
    float*       outp     = (float*)d_out;

    void* args[] = { &settings, &noiseA, &noiseB, &WinA, &WrecA, &WinB, &WrecB,
                     &Wx, &bg, &Wout, &bout, &outp, &ws };
    hipLaunchCooperativeKernel((void*)loop_kernel, dim3(NBLK), dim3(NT),
                               args, 0, stream);
}

// Round 18
// 3767.800 us; speedup vs baseline: 5.1901x; 5.0431x over previous
//
#include <hip/hip_runtime.h>
#include <cmath>

#define B_ 256
#define T_ 512
#define WASH 64
#define TOUT 448
#define NT 512
#define NBLK 256

/* ---- ws layout (float index) ---- */
#define SRING_OFF 0               /* [4][2][256][256] state ring        */
#define LRING_OFF 524288          /* [4][32 rg8][4 cb][16] logit parts  */
#define SFLAG_OFF 532480          /* [2][64 rg4] stride 32 dwords       */
#define LFLAG_OFF 536576          /* [32 rg8][4 cb] stride 32 dwords    */

__global__ void init_kernel(float* ws) {
    const int i = blockIdx.x * blockDim.x + threadIdx.x;
    if (i < 8192)
        __hip_atomic_store((unsigned*)(ws + SFLAG_OFF) + i, 0u,
                           __ATOMIC_RELAXED, __HIP_MEMORY_SCOPE_AGENT);
}

__global__ void __launch_bounds__(NT, 2)          /* 2 waves/EU -> 256-reg budget */
loop_kernel(const int* __restrict__ settings, const float* __restrict__ noiseA,
            const float* __restrict__ noiseB, const float* __restrict__ WinA,
            const float* __restrict__ WrecA, const float* __restrict__ WinB,
            const float* __restrict__ WrecB, const float* __restrict__ Wx,
            const float* __restrict__ bg, const float* __restrict__ Wout,
            const float* __restrict__ bout, float* __restrict__ out, float* ws)
{
    __shared__ float part_raw[8 * 64 * 17];  /* k-split partials */
    __shared__ float xbuf[516][8];       /* GRU: x transposed, half-swizzled   */
    __shared__ float sloc[256][4];       /* RES: persistent local state        */
    __shared__ float hz[64][9];          /* GRU: sigmoid(z)                    */
    __shared__ float hn[64][9];          /* GRU: tanh(n)                       */
    __shared__ float bitsf[4];           /* RES */
    __shared__ float dlybuf[4];          /* RES */

    const int tid = threadIdx.x;
    const int bid = blockIdx.x;
    unsigned* sflag = (unsigned*)(ws + SFLAG_OFF);
    unsigned* lflag = (unsigned*)(ws + LFLAG_OFF);
    float* sring = ws + SRING_OFF;
    float* lring = ws + LRING_OFF;
    float* out0 = out;
    float* out1 = out + (size_t)B_ * TOUT;
    float* out2 = out + (size_t)2 * B_ * TOUT;

    if (bid < 128) {
        /* ========== RESERVOIR block: side, 4 rows, FULL side Wrec in regs ==== */
        float (*part)[64][17] = (float (*)[64][17])part_raw;
        const int side = bid & 1, rg4 = bid >> 1;
        const int r0 = rg4 * 4, rg8 = rg4 >> 1, row8b = (rg4 & 1) * 4;
        const int kq = tid >> 6, cg = tid & 63;
        const float* Wr = side ? WrecB : WrecA;
        const float* Wi = side ? WinB : WinA;

        float4 w[32];                                   /* 128 weight VGPRs */
        #pragma unroll
        for (int i = 0; i < 32; ++i)
            w[i] = *(const float4*)(Wr + (size_t)(kq * 32 + i) * 256 + cg * 4);

        const int col = tid >> 1, rp = (tid & 1) * 2;
        const float win0 = Wi[col], win1 = Wi[256 + col];
        const float bo = bout[side];

        for (int i = tid; i < 1024; i += NT) ((float*)sloc)[i] = 0.f;
        __syncthreads();

        for (int t = 0; t < T_ + 2; ++t) {
            /* ---- poll logit flags >= t-1 (logit(t-2) ready); relaxed only ---- */
            if (t >= 2 && tid < 4) {
                unsigned* f = lflag + (rg8 * 4 + tid) * 32;
                int g = 0;
                while (__hip_atomic_load(f, __ATOMIC_RELAXED, __HIP_MEMORY_SCOPE_AGENT)
                       < (unsigned)(t - 1)) {
                    __builtin_amdgcn_s_sleep(1);
                    if (++g > 80000) break;
                }
            }
            __syncthreads();

            /* ---- P1: GEMM -> part ; threads 0..7: bits / delayed+signs ---- */
            if (tid < 4) {
                bitsf[tid] = (t < T_)
                    ? (float)settings[((size_t)(r0 + tid) * T_ + t) * 2 + side] : 0.f;
            } else if (tid < 8) {
                const int rr = tid - 4;
                float s = 0.f;
                if (t >= 2) {
                    const float* lb = lring + ((((size_t)((t - 2) & 3)) * 32 + rg8) * 4) * 16
                                      + (row8b + rr) * 2 + side;
                    #pragma unroll
                    for (int cb = 0; cb < 4; ++cb)
                        s += __hip_atomic_load(lb + cb * 16, __ATOMIC_RELAXED,
                                               __HIP_MEMORY_SCOPE_AGENT);
                    s += bo;
                    if (t - 2 >= WASH) {
                        const float sg = (s > 0.f) ? 1.f : ((s < 0.f) ? -1.f : 0.f);
                        __builtin_nontemporal_store(sg,
                            (side ? out1 : out0) + (size_t)(r0 + rr) * TOUT + (t - 2 - WASH));
                    }
                }
                dlybuf[rr] = s;
            }
            if (t < T_) {
                float a00=0,a01=0,a02=0,a03=0, a10=0,a11=0,a12=0,a13=0;
                float a20=0,a21=0,a22=0,a23=0, a30=0,a31=0,a32=0,a33=0;
                #pragma unroll
                for (int i = 0; i < 32; ++i) {
                    const float4 w4 = w[i];
                    const float4 s4 = *(const float4*)&sloc[kq * 32 + i][0];
                    a00 = fmaf(s4.x, w4.x, a00); a10 = fmaf(s4.y, w4.x, a10);
                    a20 = fmaf(s4.z, w4.x, a20); a30 = fmaf(s4.w, w4.x, a30);
                    a01 = fmaf(s4.x, w4.y, a01); a11 = fmaf(s4.y, w4.y, a11);
                    a21 = fmaf(s4.z, w4.y, a21); a31 = fmaf(s4.w, w4.y, a31);
                    a02 = fmaf(s4.x, w4.z, a02); a12 = fmaf(s4.y, w4.z, a12);
                    a22 = fmaf(s4.z, w4.z, a22); a32 = fmaf(s4.w, w4.z, a32);
                    a03 = fmaf(s4.x, w4.w, a03); a13 = fmaf(s4.y, w4.w, a13);
                    a23 = fmaf(s4.z, w4.w, a23); a33 = fmaf(s4.w, w4.w, a33);
                }
                float* pb = &part[kq][cg][0];
                pb[0]=a00; pb[1]=a10; pb[2]=a20; pb[3]=a30;
                pb[4]=a01; pb[5]=a11; pb[6]=a21; pb[7]=a31;
                pb[8]=a02; pb[9]=a12; pb[10]=a22; pb[11]=a32;
                pb[12]=a03; pb[13]=a13; pb[14]=a23; pb[15]=a33;
            }
            __syncthreads();

            /* ---- P2: reduce + inputs + tanh -> sloc ---- */
            if (t < T_) {
                #pragma unroll
                for (int r = 0; r < 2; ++r) {
                    float e = 0.f;
                    #pragma unroll
                    for (int q = 0; q < 8; ++q)
                        e += part[q][col >> 2][(col & 3) * 4 + rp + r];
                    e += bitsf[rp + r] * win0 + dlybuf[rp + r] * win1;
                    sloc[col][rp + r] = tanhf(e);
                }
            }
            __syncthreads();

            /* ---- P3: contiguous publish + flag ---- */
            if (t < T_) {
                #pragma unroll
                for (int e = 0; e < 2; ++e) {
                    const int idx = tid + e * NT;
                    const int prow = idx >> 8, pcol = idx & 255;
                    __hip_atomic_store(
                        sring + ((size_t)(((t + 1) & 3) * 2 + side) * 256 + r0 + prow) * 256 + pcol,
                        sloc[pcol][prow], __ATOMIC_RELAXED, __HIP_MEMORY_SCOPE_AGENT);
                }
            }
            __syncthreads();
            if (t < T_ && tid == 0) {
                asm volatile("s_waitcnt vmcnt(0)" ::: "memory");
                __hip_atomic_fetch_add(sflag + (side * 64 + rg4) * 32, 1u,
                                       __ATOMIC_RELAXED, __HIP_MEMORY_SCOPE_AGENT);
            }
        }
    } else {
        /* ========== GRU block: 8 rows x 64 h-dims, Wx slice in regs ========== */
        float (*partG)[64][17] = (float (*)[64][17])part_raw;
        const int g = bid - 128, rg8 = g >> 2, cb = g & 3, r0 = rg8 * 8;
        const int kq = tid >> 6, c2 = tid & 63;
        const int zcol = cb * 64 + c2, ncol = 512 + zcol;

        float wz[66], wn[66];                            /* 132 weight regs */
        #pragma unroll
        for (int i = 0; i < 66; ++i) {
            const int k = kq * 64 + i;
            const bool v = (i < 64) || (kq == 7);
            wz[i] = v ? Wx[(size_t)k * 768 + zcol] : 0.f;
            wn[i] = v ? Wx[(size_t)k * 768 + ncol] : 0.f;
        }
        const int hd = tid >> 3, rs4 = (tid >> 1) & 3, zn = tid & 1;
        const float bgr = zn ? bg[512 + cb * 64 + hd] : bg[cb * 64 + hd];
        const int wv = tid >> 6, lane = tid & 63, lj = wv & 1;
        const float wo = Wout[(cb * 64 + lane) * 2 + lj];

        const int xk = tid;
        const int sd = (xk < 256) ? 0 : 1;
        const int nc0 = xk & 255;
        const float* npb = (sd ? noiseB : noiseA) + (size_t)r0 * T_ * 256 + nc0;
        float nz[8];
        #pragma unroll
        for (int r = 0; r < 8; ++r) nz[r] = npb[(size_t)r * T_ * 256];

        for (int u = 0; u < T_; ++u) {
            /* ---- poll state flags >= u (relaxed only) ---- */
            if (u > 0 && tid < 4) {
                unsigned* f = sflag + ((tid & 1) * 64 + rg8 * 2 + (tid >> 1)) * 32;
                int gg = 0;
                while (__hip_atomic_load(f, __ATOMIC_RELAXED, __HIP_MEMORY_SCOPE_AGENT)
                       < (unsigned)u) {
                    __builtin_amdgcn_s_sleep(1);
                    if (++gg > 80000) break;
                }
            }
            __syncthreads();

            /* ---- B: x-build (gather state + noise, 8 rows/thread) ---- */
            {
                float sv[8];
                #pragma unroll
                for (int r = 0; r < 8; ++r) sv[r] = 0.f;
                if (u > 0) {
                    const float* sb = sring
                        + ((size_t)((u & 3) * 2 + sd) * 256 + r0) * 256 + nc0;
                    #pragma unroll
                    for (int r = 0; r < 8; ++r)
                        sv[r] = __hip_atomic_load(sb + (size_t)r * 256,
                                                  __ATOMIC_RELAXED, __HIP_MEMORY_SCOPE_AGENT);
                }
                const int b = (xk >> 2) & 1;
                *(float4*)&xbuf[xk][4 * b] =
                    make_float4(sv[0] + nz[0], sv[1] + nz[1], sv[2] + nz[2], sv[3] + nz[3]);
                *(float4*)&xbuf[xk][4 - 4 * b] =
                    make_float4(sv[4] + nz[4], sv[5] + nz[5], sv[6] + nz[6], sv[7] + nz[7]);
            }
            if (tid < 16) {                          /* spins + settings log */
                const int rr = tid >> 1, jj = tid & 1;
                const int bv = settings[((size_t)(r0 + rr) * T_ + u) * 2 + jj];
                xbuf[512 + jj][rr] = 2.f * (float)bv - 1.f;
                if (cb == 0 && u >= WASH)
                    __builtin_nontemporal_store((float)bv,
                        out2 + ((size_t)(r0 + rr) * TOUT + (u - WASH)) * 2 + jj);
            }
            __syncthreads();

            /* ---- C: GEMM -> partG ; prefetch next noise ---- */
            {
                const int un = (u + 1 < T_) ? u + 1 : u;
                #pragma unroll
                for (int r = 0; r < 8; ++r)
                    nz[r] = npb[(size_t)r * T_ * 256 + (size_t)un * 256];

                float az0=0,az1=0,az2=0,az3=0,az4=0,az5=0,az6=0,az7=0;
                float an0=0,an1=0,an2=0,an3=0,an4=0,an5=0,an6=0,an7=0;
                #pragma unroll
                for (int i = 0; i < 66; ++i) {
                    const int k = kq * 64 + i;
                    const int bsw = (k >> 2) & 1;
                    const float4 xa = *(const float4*)&xbuf[k][4 * bsw];       /* rows 0-3 */
                    const float4 xb = *(const float4*)&xbuf[k][4 - 4 * bsw];   /* rows 4-7 */
                    const float wzi = wz[i], wni = wn[i];
                    az0 = fmaf(xa.x, wzi, az0); az1 = fmaf(xa.y, wzi, az1);
                    az2 = fmaf(xa.z, wzi, az2); az3 = fmaf(xa.w, wzi, az3);
                    az4 = fmaf(xb.x, wzi, az4); az5 = fmaf(xb.y, wzi, az5);
                    az6 = fmaf(xb.z, wzi, az6); az7 = fmaf(xb.w, wzi, az7);
                    an0 = fmaf(xa.x, wni, an0); an1 = fmaf(xa.y, wni, an1);
                    an2 = fmaf(xa.z, wni, an2); an3 = fmaf(xa.w, wni, an3);
                    an4 = fmaf(xb.x, wni, an4); an5 = fmaf(xb.y, wni, an5);
                    an6 = fmaf(xb.z, wni, an6); an7 = fmaf(xb.w, wni, an7);
                }
                float* pb = &partG[kq][c2][0];
                pb[0]=az0;  pb[1]=an0;  pb[2]=az1;  pb[3]=an1;
                pb[4]=az2;  pb[5]=an2;  pb[6]=az3;  pb[7]=an3;
                pb[8]=az4;  pb[9]=an4;  pb[10]=az5; pb[11]=an5;
                pb[12]=az6; pb[13]=an6; pb[14]=az7; pb[15]=an7;
            }
            __syncthreads();

            /* ---- D: reduce + activations (2 outputs/thread: rs4, rs4+4) ---- */
            {
                #pragma unroll
                for (int h = 0; h < 2; ++h) {
                    const int rsub = rs4 + h * 4;
                    float e = bgr;
                    #pragma unroll
                    for (int q = 0; q < 8; ++q) e += partG[q][hd][rsub * 2 + zn];
                    if (zn == 0) hz[hd][rsub] = 1.f / (1.f + expf(-e));
                    else         hn[hd][rsub] = tanhf(e);
                }
            }
            __syncthreads();

            /* ---- E: logit partials — 8 waves x TWO reductions = 8 rows x 2 ---- */
            {
                #pragma unroll
                for (int h = 0; h < 2; ++h) {
                    const int lrow2 = (wv >> 1) + h * 4;
                    float p = (1.f - hz[lane][lrow2]) * hn[lane][lrow2] * wo;
                    #pragma unroll
                    for (int s = 32; s; s >>= 1) p += __shfl_down(p, s, 64);
                    if (lane == 0)
                        __hip_atomic_store(
                            lring + (((size_t)(u & 3) * 32 + rg8) * 4 + cb) * 16 + lrow2 * 2 + lj,
                            p, __ATOMIC_RELAXED, __HIP_MEMORY_SCOPE_AGENT);
                }
            }
            __syncthreads();
            if (tid == 0) {
                asm volatile("s_waitcnt vmcnt(0)" ::: "memory");
                __hip_atomic_fetch_add(lflag + (rg8 * 4 + cb) * 32, 1u,
                                       __ATOMIC_RELAXED, __HIP_MEMORY_SCOPE_AGENT);
            }
        }
    }
}

extern "C" void kernel_launch(void* const* d_in, const int* in_sizes, int n_in,
                              void* d_out, int out_size, void* d_ws, size_t ws_size,
                              hipStream_t stream) {
    (void)in_sizes; (void)n_in; (void)ws_size; (void)out_size;
    float* ws = (float*)d_ws;
    hipLaunchKernelGGL(init_kernel, dim3(32), dim3(256), 0, stream, ws);

    const int*   settings = (const int*)d_in[0];
    const float* noiseA   = (const float*)d_in[1];
    const float* noiseB   = (const float*)d_in[2];
    const float* WinA     = (const float*)d_in[3];
    const float* WrecA    = (const float*)d_in[4];
    const float* WinB     = (const float*)d_in[5];
    const float* WrecB    = (const float*)d_in[6];
    const float* Wx       = (const float*)d_in[7];   /* d_in[8] = Wh unused (h0 == 0) */
    const float* bg       = (const float*)d_in[9];
    const float* Wout     = (const float*)d_in[10];
    const float* bout     = (const float*)d_in[11];
    float*       outp     = (float*)d_out;

    void* args[] = { &settings, &noiseA, &noiseB, &WinA, &WrecA, &WinB, &WrecB,
                     &Wx, &bg, &Wout, &bout, &outp, &ws };
    hipLaunchCooperativeKernel((void*)loop_kernel, dim3(NBLK), dim3(NT),
                               args, 0, stream);
}